// Round 6
// baseline (75.737 us; speedup 1.0000x reference)
//
#include <hip/hip_runtime.h>

#define DIM       128
#define BATCH     16384
#define RELN      500
#define ALPHA     0.001f
#define CHUNK     8
#define MAXCHUNKS (BATCH / CHUNK + RELN)   // 2548 upper bound on total chunks

__device__ __forceinline__ float dot4(float4 a, float4 b) {
    return a.x * b.x + a.y * b.y + a.z * b.z + a.w * b.w;
}

// ---------- prep: ONE block: hist + scan + scatter(+pair gather) + chunk_info ----------
__global__ void __launch_bounds__(1024) prep_kernel(
    const int* __restrict__ r_idx,
    const int* __restrict__ h_idx,
    const int* __restrict__ t_idx,
    int*  __restrict__ bucket,       // [BATCH]
    int2* __restrict__ pair,         // [BATCH] (h_idx, t_idx) in bucket order
    int4* __restrict__ chunk_info,   // [MAXCHUNKS] (rel, start, e_cnt, 0); padded
    int*  __restrict__ n_chunks)
{
    __shared__ int cnt[512];
    __shared__ int offs[512];
    __shared__ int cur[512];
    __shared__ int total_s;
    const int tid = threadIdx.x;

    if (tid < 512) cnt[tid] = 0;
    __syncthreads();

    int myr[16];
    #pragma unroll
    for (int k = 0; k < 16; ++k) {
        myr[k] = r_idx[tid + k * 1024];
        atomicAdd(&cnt[myr[k]], 1);
    }
    __syncthreads();

    // inclusive scan of cnt -> offs
    if (tid < 512) offs[tid] = cnt[tid];
    __syncthreads();
    for (int d = 1; d < 512; d <<= 1) {
        int x = 0;
        if (tid < 512 && tid >= d) x = offs[tid - d];
        __syncthreads();
        if (tid < 512) offs[tid] += x;
        __syncthreads();
    }
    int excl = 0;
    if (tid < 512) {
        excl = offs[tid] - cnt[tid];
        cur[tid] = excl;
    }
    __syncthreads();

    // scatter + pair gather (order within a relation nondeterministic;
    // no output depends on it)
    #pragma unroll
    for (int k = 0; k < 16; ++k) {
        const int b   = tid + k * 1024;
        const int pos = atomicAdd(&cur[myr[k]], 1);
        bucket[pos] = b;
        pair[pos]   = make_int2(h_idx[b], t_idx[b]);
    }

    // chunk scan over ceil(cnt/CHUNK)
    const int nc = (tid < RELN) ? (cnt[tid] + CHUNK - 1) / CHUNK : 0;
    __syncthreads();
    if (tid < 512) offs[tid] = nc;
    __syncthreads();
    for (int d = 1; d < 512; d <<= 1) {
        int x = 0;
        if (tid < 512 && tid >= d) x = offs[tid - d];
        __syncthreads();
        if (tid < 512) offs[tid] += x;
        __syncthreads();
    }
    if (tid == 511) { n_chunks[0] = offs[511]; total_s = offs[511]; }
    if (tid < RELN) {
        const int cbase = offs[tid] - nc;
        for (int i = 0; i < nc; ++i)
            chunk_info[cbase + i] = make_int4(
                tid, excl + i * CHUNK, min(CHUNK, cnt[tid] - i * CHUNK), 0);
    }
    __syncthreads();
    for (int s = total_s + tid; s < MAXCHUNKS; s += 1024)
        chunk_info[s] = make_int4(0, 0, 0, 0);
}

// ---------- main: one block per chunk of 8; R STREAMED in 4-row groups ----------
// Thread (wave w, lane l): hi=l>>5, c4=l&31; owns 16 consecutive rows
// rbase=32w+16hi and float4 col-slice c4. Per-thread state: t4[8] fragments
// (32 VGPR) + acc[8]; R streamed 4 rows at a time (#pragma unroll 1 keeps only
// 16 R-regs live -> ~70 VGPR -> 7 waves/SIMD). h applied via 2-address
// broadcast b128 LDS reads (4 rows x 1 element each). Latency hiding comes
// from occupancy, not ILP — R5's 120-VGPR full-hoist gave 4 waves/SIMD and
// stalled. All reduction trees slot-invariant -> bit-deterministic.
__global__ void __launch_bounds__(256) rescal_main_kernel(
    const int4*  __restrict__ chunk_info,
    const int2*  __restrict__ pair,
    const int*   __restrict__ bucket,
    const float* __restrict__ labels,
    const float* __restrict__ ent_w,
    const float* __restrict__ rel_w,
    float*       __restrict__ scores_out,   // d_out + 1
    float2*      __restrict__ partials,     // [BATCH] (err, h2+t2)
    float*       __restrict__ chunk_r2)     // [MAXCHUNKS] e_cnt * ||R||^2
{
    // bijective XCD swizzle: consecutive cids (same relation) share an XCD L2
    const int bid = blockIdx.x;
    const int xcd = bid & 7;
    const int j   = bid >> 3;
    const int q   = MAXCHUNKS / 8;
    const int r_  = MAXCHUNKS % 8;
    const int cid = (xcd < r_ ? xcd * (q + 1) : r_ * (q + 1) + (xcd - r_) * q) + j;

    const int4 ci    = chunk_info[cid];
    const int  rel   = ci.x;
    const int  start = ci.y;
    const int  e_cnt = ci.z;
    if (e_cnt == 0) return;                  // padded slot

    const int tid = threadIdx.x;
    const int w   = tid >> 6;
    const int l   = tid & 63;
    const int hi  = l >> 5;
    const int c4  = l & 31;
    const int rbase = 32 * w + 16 * hi;

    __shared__ float t_lds[CHUNK][DIM];
    __shared__ float h_lds[CHUNK][DIM];
    __shared__ float red[4][CHUNK];
    __shared__ float ht_red[CHUNK];
    __shared__ float r2_red[4];

    // ---- stage t, h (32 threads per element, 1 float4 each) ----
    const int eg   = tid >> 5;
    const int col4 = tid & 31;
    float4 tv4 = make_float4(0.f, 0.f, 0.f, 0.f);
    float4 hv4 = tv4;
    if (eg < e_cnt) {
        const int2 p2 = pair[start + eg];
        hv4 = *(const float4*)(ent_w + (size_t)p2.x * DIM + col4 * 4);
        tv4 = *(const float4*)(ent_w + (size_t)p2.y * DIM + col4 * 4);
    }
    *(float4*)&t_lds[eg][col4 * 4] = tv4;
    *(float4*)&h_lds[eg][col4 * 4] = hv4;

    float htp = dot4(tv4, tv4) + dot4(hv4, hv4);
    #pragma unroll
    for (int off = 16; off >= 1; off >>= 1) htp += __shfl_xor(htp, off);
    if ((tid & 31) == 0) ht_red[eg] = htp;
    __syncthreads();

    // ---- t fragments to registers (b128, conflict-free) ----
    float4 t4[CHUNK];
    #pragma unroll
    for (int e = 0; e < CHUNK; ++e)
        t4[e] = *(const float4*)&t_lds[e][c4 * 4];

    // ---- stream R in 4-row groups ----
    const float4* Rb = (const float4*)(rel_w + (size_t)rel * (DIM * DIM)
                                             + (size_t)rbase * DIM) + c4;
    float acc[CHUNK];
    #pragma unroll
    for (int e = 0; e < CHUNK; ++e) acc[e] = 0.f;
    float r2 = 0.f;

    #pragma unroll 1
    for (int pg = 0; pg < 4; ++pg) {
        const float4 r0 = Rb[(4 * pg + 0) * (DIM / 4)];
        const float4 r1 = Rb[(4 * pg + 1) * (DIM / 4)];
        const float4 rq = Rb[(4 * pg + 2) * (DIM / 4)];
        const float4 r3 = Rb[(4 * pg + 3) * (DIM / 4)];
        r2 += dot4(r0, r0) + dot4(r1, r1) + dot4(rq, rq) + dot4(r3, r3);
        #pragma unroll
        for (int e = 0; e < CHUNK; ++e) {
            const float4 h4 = *(const float4*)&h_lds[e][rbase + 4 * pg];
            acc[e] += h4.x * dot4(r0, t4[e]) + h4.y * dot4(r1, t4[e])
                    + h4.z * dot4(rq, t4[e]) + h4.w * dot4(r3, t4[e]);
        }
    }

    // ---- reductions (slot-invariant trees) ----
    #pragma unroll
    for (int off = 32; off >= 1; off >>= 1) r2 += __shfl_xor(r2, off);
    if (l == 0) r2_red[w] = r2;

    #pragma unroll
    for (int e = 0; e < CHUNK; ++e) {
        float v = acc[e];
        #pragma unroll
        for (int off = 32; off >= 1; off >>= 1) v += __shfl_xor(v, off);
        if (l == 0) red[w][e] = v;
    }
    __syncthreads();

    if (tid == 0)
        chunk_r2[cid] = (float)e_cnt *
            (r2_red[0] + r2_red[1] + r2_red[2] + r2_red[3]);

    if (tid < e_cnt) {
        const float s  = red[0][tid] + red[1][tid] + red[2][tid] + red[3][tid];
        const int   bb = bucket[start + tid];
        scores_out[bb] = s;
        const float d  = s - labels[bb];
        partials[bb] = make_float2(d * d, ht_red[tid]);
    }
}

// ---------- final: fixed-order reduction -> loss ----------
__global__ void __launch_bounds__(512) final_kernel(
    const float2* __restrict__ partials,
    const float*  __restrict__ chunk_r2,
    const int*    __restrict__ n_chunks,
    float*        __restrict__ loss_out)
{
    const int tid = threadIdx.x;
    const int total = n_chunks[0];
    float err = 0.f, ht = 0.f, r2 = 0.f;
    for (int i = tid; i < BATCH; i += 512) {
        const float2 p = partials[i];
        err += p.x; ht += p.y;
    }
    for (int i = tid; i < total; i += 512) r2 += chunk_r2[i];

    __shared__ float re[8], rh[8], rr2[8];
    #pragma unroll
    for (int off = 32; off >= 1; off >>= 1) {
        err += __shfl_down(err, off);
        ht  += __shfl_down(ht, off);
        r2  += __shfl_down(r2, off);
    }
    if ((tid & 63) == 0) { const int v = tid >> 6; re[v] = err; rh[v] = ht; rr2[v] = r2; }
    __syncthreads();
    if (tid == 0) {
        err = 0.f; ht = 0.f; r2 = 0.f;
        for (int v = 0; v < 8; ++v) { err += re[v]; ht += rh[v]; r2 += rr2[v]; }
        const float mse   = err / (float)BATCH;
        const float norms = (ht / ((float)BATCH * DIM)
                           + r2 / ((float)BATCH * (float)(DIM * DIM))) / 3.0f;
        loss_out[0] = mse + ALPHA * norms;
    }
}

extern "C" void kernel_launch(void* const* d_in, const int* in_sizes, int n_in,
                              void* d_out, int out_size, void* d_ws, size_t ws_size,
                              hipStream_t stream) {
    const int*   h_idx  = (const int*)d_in[0];
    const int*   r_idx  = (const int*)d_in[1];
    const int*   t_idx  = (const int*)d_in[2];
    const float* labels = (const float*)d_in[3];
    const float* ent_w  = (const float*)d_in[4];
    const float* rel_w  = (const float*)d_in[5];

    float* out = (float*)d_out;   // [0]=loss, [1..BATCH]=scores

    // workspace layout (~375 KB)
    char* ws = (char*)d_ws;
    float2* partials   = (float2*)ws;           ws += BATCH * sizeof(float2);
    int2*   pair       = (int2*)ws;             ws += BATCH * sizeof(int2);
    int*    bucket     = (int*)ws;              ws += BATCH * sizeof(int);
    int4*   chunk_info = (int4*)ws;             ws += MAXCHUNKS * sizeof(int4);
    float*  chunk_r2   = (float*)ws;            ws += MAXCHUNKS * sizeof(float);
    int*    n_chunks   = (int*)ws;

    prep_kernel<<<1, 1024, 0, stream>>>(r_idx, h_idx, t_idx,
                                        bucket, pair, chunk_info, n_chunks);
    rescal_main_kernel<<<MAXCHUNKS, 256, 0, stream>>>(
        chunk_info, pair, bucket, labels, ent_w, rel_w,
        out + 1, partials, chunk_r2);
    final_kernel<<<1, 512, 0, stream>>>(partials, chunk_r2, n_chunks, out);
}

// Round 7
// 58.990 us; speedup vs baseline: 1.2839x; 1.2839x over previous
//
#include <hip/hip_runtime.h>

#define DIM       128
#define BATCH     16384
#define RELN      500
#define ALPHA     0.001f
#define CHUNK     8
#define MAXCHUNKS (BATCH / CHUNK + RELN)   // 2548 upper bound on total chunks

__device__ __forceinline__ float dot4(float4 a, float4 b) {
    return a.x * b.x + a.y * b.y + a.z * b.z + a.w * b.w;
}

// ---------- prep 1: per-block LDS histogram -> plain partial writes ----------
__global__ void __launch_bounds__(256) parthist_kernel(
    const int* __restrict__ r_idx,
    int*       __restrict__ partial)     // [64][512]
{
    __shared__ int cnt[512];
    const int tid = threadIdx.x;
    cnt[tid] = 0; cnt[tid + 256] = 0;
    __syncthreads();
    atomicAdd(&cnt[r_idx[blockIdx.x * 256 + tid]], 1);
    __syncthreads();
    partial[blockIdx.x * 512 + tid]       = cnt[tid];
    partial[blockIdx.x * 512 + tid + 256] = cnt[tid + 256];
}

// ---------- prep 2: single block: reduce partials, scan, build chunk_info ----------
__global__ void __launch_bounds__(512) scan_kernel(
    const int* __restrict__ partial,     // [64][512]
    int*  __restrict__ cursor,           // [512]
    int4* __restrict__ chunk_info,       // [MAXCHUNKS] (rel, start, e_cnt, 0)
    int*  __restrict__ n_chunks)
{
    __shared__ int s[512];
    __shared__ int total_s;
    const int tid = threadIdx.x;

    int cnt = 0;
    #pragma unroll 8
    for (int b = 0; b < 64; ++b) cnt += partial[b * 512 + tid];   // coalesced

    s[tid] = cnt;
    __syncthreads();
    for (int d = 1; d < 512; d <<= 1) {
        const int x = (tid >= d) ? s[tid - d] : 0;
        __syncthreads();
        s[tid] += x;
        __syncthreads();
    }
    const int excl = s[tid] - cnt;
    cursor[tid] = excl;

    const int nc = (tid < RELN) ? (cnt + CHUNK - 1) / CHUNK : 0;
    __syncthreads();
    s[tid] = nc;
    __syncthreads();
    for (int d = 1; d < 512; d <<= 1) {
        const int x = (tid >= d) ? s[tid - d] : 0;
        __syncthreads();
        s[tid] += x;
        __syncthreads();
    }
    if (tid == 511) { n_chunks[0] = s[511]; total_s = s[511]; }
    const int cbase = s[tid] - nc;
    for (int i = 0; i < nc; ++i)
        chunk_info[cbase + i] = make_int4(
            tid, excl + i * CHUNK, min(CHUNK, cnt - i * CHUNK), 0);
    __syncthreads();
    for (int p = total_s + tid; p < MAXCHUNKS; p += 512)
        chunk_info[p] = make_int4(0, 0, 0, 0);
}

// ---------- prep 3: multi-block scatter + pair gather ----------
__global__ void __launch_bounds__(256) scatter_kernel(
    const int* __restrict__ r_idx,
    const int* __restrict__ h_idx,
    const int* __restrict__ t_idx,
    int*  __restrict__ cursor,
    int*  __restrict__ bucket,           // [BATCH]
    int2* __restrict__ pair)             // [BATCH] (h_idx, t_idx) bucket order
{
    const int i   = blockIdx.x * 256 + threadIdx.x;
    const int pos = atomicAdd(&cursor[r_idx[i]], 1);
    bucket[pos] = i;
    pair[pos]   = make_int2(h_idx[i], t_idx[i]);
}

// ---------- main: one block per chunk of 8; R STREAMED in 4-row groups ----------
// (unchanged from R6 — proven ~12 µs)
__global__ void __launch_bounds__(256) rescal_main_kernel(
    const int4*  __restrict__ chunk_info,
    const int2*  __restrict__ pair,
    const int*   __restrict__ bucket,
    const float* __restrict__ labels,
    const float* __restrict__ ent_w,
    const float* __restrict__ rel_w,
    float*       __restrict__ scores_out,   // d_out + 1
    float2*      __restrict__ partials,     // [BATCH] (err, h2+t2)
    float*       __restrict__ chunk_r2)     // [MAXCHUNKS] e_cnt * ||R||^2
{
    const int bid = blockIdx.x;
    const int xcd = bid & 7;
    const int j   = bid >> 3;
    const int q   = MAXCHUNKS / 8;
    const int r_  = MAXCHUNKS % 8;
    const int cid = (xcd < r_ ? xcd * (q + 1) : r_ * (q + 1) + (xcd - r_) * q) + j;

    const int4 ci    = chunk_info[cid];
    const int  rel   = ci.x;
    const int  start = ci.y;
    const int  e_cnt = ci.z;
    if (e_cnt == 0) return;                  // padded slot

    const int tid = threadIdx.x;
    const int w   = tid >> 6;
    const int l   = tid & 63;
    const int hi  = l >> 5;
    const int c4  = l & 31;
    const int rbase = 32 * w + 16 * hi;

    __shared__ float t_lds[CHUNK][DIM];
    __shared__ float h_lds[CHUNK][DIM];
    __shared__ float red[4][CHUNK];
    __shared__ float ht_red[CHUNK];
    __shared__ float r2_red[4];

    const int eg   = tid >> 5;
    const int col4 = tid & 31;
    float4 tv4 = make_float4(0.f, 0.f, 0.f, 0.f);
    float4 hv4 = tv4;
    if (eg < e_cnt) {
        const int2 p2 = pair[start + eg];
        hv4 = *(const float4*)(ent_w + (size_t)p2.x * DIM + col4 * 4);
        tv4 = *(const float4*)(ent_w + (size_t)p2.y * DIM + col4 * 4);
    }
    *(float4*)&t_lds[eg][col4 * 4] = tv4;
    *(float4*)&h_lds[eg][col4 * 4] = hv4;

    float htp = dot4(tv4, tv4) + dot4(hv4, hv4);
    #pragma unroll
    for (int off = 16; off >= 1; off >>= 1) htp += __shfl_xor(htp, off);
    if ((tid & 31) == 0) ht_red[eg] = htp;
    __syncthreads();

    float4 t4[CHUNK];
    #pragma unroll
    for (int e = 0; e < CHUNK; ++e)
        t4[e] = *(const float4*)&t_lds[e][c4 * 4];

    const float4* Rb = (const float4*)(rel_w + (size_t)rel * (DIM * DIM)
                                             + (size_t)rbase * DIM) + c4;
    float acc[CHUNK];
    #pragma unroll
    for (int e = 0; e < CHUNK; ++e) acc[e] = 0.f;
    float r2 = 0.f;

    #pragma unroll 1
    for (int pg = 0; pg < 4; ++pg) {
        const float4 r0 = Rb[(4 * pg + 0) * (DIM / 4)];
        const float4 r1 = Rb[(4 * pg + 1) * (DIM / 4)];
        const float4 rq = Rb[(4 * pg + 2) * (DIM / 4)];
        const float4 r3 = Rb[(4 * pg + 3) * (DIM / 4)];
        r2 += dot4(r0, r0) + dot4(r1, r1) + dot4(rq, rq) + dot4(r3, r3);
        #pragma unroll
        for (int e = 0; e < CHUNK; ++e) {
            const float4 h4 = *(const float4*)&h_lds[e][rbase + 4 * pg];
            acc[e] += h4.x * dot4(r0, t4[e]) + h4.y * dot4(r1, t4[e])
                    + h4.z * dot4(rq, t4[e]) + h4.w * dot4(r3, t4[e]);
        }
    }

    #pragma unroll
    for (int off = 32; off >= 1; off >>= 1) r2 += __shfl_xor(r2, off);
    if (l == 0) r2_red[w] = r2;

    #pragma unroll
    for (int e = 0; e < CHUNK; ++e) {
        float v = acc[e];
        #pragma unroll
        for (int off = 32; off >= 1; off >>= 1) v += __shfl_xor(v, off);
        if (l == 0) red[w][e] = v;
    }
    __syncthreads();

    if (tid == 0)
        chunk_r2[cid] = (float)e_cnt *
            (r2_red[0] + r2_red[1] + r2_red[2] + r2_red[3]);

    if (tid < e_cnt) {
        const float s  = red[0][tid] + red[1][tid] + red[2][tid] + red[3][tid];
        const int   bb = bucket[start + tid];
        scores_out[bb] = s;
        const float d  = s - labels[bb];
        partials[bb] = make_float2(d * d, ht_red[tid]);
    }
}

// ---------- final: fixed-order reduction -> loss ----------
__global__ void __launch_bounds__(512) final_kernel(
    const float2* __restrict__ partials,
    const float*  __restrict__ chunk_r2,
    const int*    __restrict__ n_chunks,
    float*        __restrict__ loss_out)
{
    const int tid = threadIdx.x;
    const int total = n_chunks[0];
    float err = 0.f, ht = 0.f, r2 = 0.f;
    for (int i = tid; i < BATCH; i += 512) {
        const float2 p = partials[i];
        err += p.x; ht += p.y;
    }
    for (int i = tid; i < total; i += 512) r2 += chunk_r2[i];

    __shared__ float re[8], rh[8], rr2[8];
    #pragma unroll
    for (int off = 32; off >= 1; off >>= 1) {
        err += __shfl_down(err, off);
        ht  += __shfl_down(ht, off);
        r2  += __shfl_down(r2, off);
    }
    if ((tid & 63) == 0) { const int v = tid >> 6; re[v] = err; rh[v] = ht; rr2[v] = r2; }
    __syncthreads();
    if (tid == 0) {
        err = 0.f; ht = 0.f; r2 = 0.f;
        for (int v = 0; v < 8; ++v) { err += re[v]; ht += rh[v]; r2 += rr2[v]; }
        const float mse   = err / (float)BATCH;
        const float norms = (ht / ((float)BATCH * DIM)
                           + r2 / ((float)BATCH * (float)(DIM * DIM))) / 3.0f;
        loss_out[0] = mse + ALPHA * norms;
    }
}

extern "C" void kernel_launch(void* const* d_in, const int* in_sizes, int n_in,
                              void* d_out, int out_size, void* d_ws, size_t ws_size,
                              hipStream_t stream) {
    const int*   h_idx  = (const int*)d_in[0];
    const int*   r_idx  = (const int*)d_in[1];
    const int*   t_idx  = (const int*)d_in[2];
    const float* labels = (const float*)d_in[3];
    const float* ent_w  = (const float*)d_in[4];
    const float* rel_w  = (const float*)d_in[5];

    float* out = (float*)d_out;   // [0]=loss, [1..BATCH]=scores

    // workspace layout (~372 KB). `pair` ALIASES `partial_hist` (dead after scan).
    char* ws = (char*)d_ws;
    float2* partials   = (float2*)ws;           ws += BATCH * sizeof(float2);      // 128K
    int*    bucket     = (int*)ws;              ws += BATCH * sizeof(int);         // 64K
    int4*   chunk_info = (int4*)ws;             ws += MAXCHUNKS * sizeof(int4);    // ~40K
    float*  chunk_r2   = (float*)ws;            ws += MAXCHUNKS * sizeof(float);   // ~10K
    int*    cursor     = (int*)ws;              ws += 512 * sizeof(int);           // 2K
    int*    n_chunks   = (int*)ws;              ws += 256;                         // align
    int*    partial_h  = (int*)ws;              // 64*512*4 = 128K  (union w/ pair)
    int2*   pair       = (int2*)ws;             // BATCH*8 = 128K   (after scan)

    parthist_kernel<<<BATCH / 256, 256, 0, stream>>>(r_idx, partial_h);
    scan_kernel<<<1, 512, 0, stream>>>(partial_h, cursor, chunk_info, n_chunks);
    scatter_kernel<<<BATCH / 256, 256, 0, stream>>>(r_idx, h_idx, t_idx,
                                                    cursor, bucket, pair);
    rescal_main_kernel<<<MAXCHUNKS, 256, 0, stream>>>(
        chunk_info, pair, bucket, labels, ent_w, rel_w,
        out + 1, partials, chunk_r2);
    final_kernel<<<1, 512, 0, stream>>>(partials, chunk_r2, n_chunks, out);
}

// Round 8
// 50.227 us; speedup vs baseline: 1.5079x; 1.1745x over previous
//
#include <hip/hip_runtime.h>

#define DIM       128
#define BATCH     16384
#define RELN      500
#define ALPHA     0.001f
#define CHUNK     8
#define MAXCHUNKS (BATCH / CHUNK + RELN)   // 2548 upper bound on total chunks
#define NHBLK     (BATCH / 256)            // 64 hist/scatter blocks

__device__ __forceinline__ float dot4(float4 a, float4 b) {
    return a.x * b.x + a.y * b.y + a.z * b.z + a.w * b.w;
}

// ---------- K1: per-block LDS histogram -> plain partial writes ----------
__global__ void __launch_bounds__(256) parthist_kernel(
    const int* __restrict__ r_idx,
    int*       __restrict__ partial)     // [NHBLK][512]
{
    __shared__ int cnt[512];
    const int tid = threadIdx.x;
    cnt[tid] = 0; cnt[tid + 256] = 0;
    __syncthreads();
    atomicAdd(&cnt[r_idx[blockIdx.x * 256 + tid]], 1);
    __syncthreads();
    partial[blockIdx.x * 512 + tid]       = cnt[tid];
    partial[blockIdx.x * 512 + tid + 256] = cnt[tid + 256];
}

// ---------- K2: single block: totals, scan, per-histblock offsets, chunk_info ----------
__global__ void __launch_bounds__(512) scan_kernel(
    const int* __restrict__ partial,     // [NHBLK][512]
    int*  __restrict__ blockoff,         // [NHBLK][512]
    int4* __restrict__ chunk_info,       // [MAXCHUNKS] (rel, start, e_cnt, 0)
    int*  __restrict__ n_chunks)
{
    __shared__ int s[512];
    __shared__ int total_s;
    const int tid = threadIdx.x;

    int cnt = 0;
    #pragma unroll 8
    for (int b = 0; b < NHBLK; ++b) cnt += partial[b * 512 + tid];   // coalesced

    s[tid] = cnt;
    __syncthreads();
    for (int d = 1; d < 512; d <<= 1) {
        const int x = (tid >= d) ? s[tid - d] : 0;
        __syncthreads();
        s[tid] += x;
        __syncthreads();
    }
    const int excl = s[tid] - cnt;

    // per-histblock running offsets (coalesced writes; partial re-reads are L2-hot)
    int run = excl;
    #pragma unroll 8
    for (int b = 0; b < NHBLK; ++b) {
        blockoff[b * 512 + tid] = run;
        run += partial[b * 512 + tid];
    }

    // chunk list scan over ceil(cnt/CHUNK)
    const int nc = (tid < RELN) ? (cnt + CHUNK - 1) / CHUNK : 0;
    __syncthreads();
    s[tid] = nc;
    __syncthreads();
    for (int d = 1; d < 512; d <<= 1) {
        const int x = (tid >= d) ? s[tid - d] : 0;
        __syncthreads();
        s[tid] += x;
        __syncthreads();
    }
    if (tid == 511) { n_chunks[0] = s[511]; total_s = s[511]; }
    const int cbase = s[tid] - nc;
    for (int i = 0; i < nc; ++i)
        chunk_info[cbase + i] = make_int4(
            tid, excl + i * CHUNK, min(CHUNK, cnt - i * CHUNK), 0);
    __syncthreads();
    for (int p = total_s + tid; p < MAXCHUNKS; p += 512)
        chunk_info[p] = make_int4(0, 0, 0, 0);
}

// ---------- K3: scatter via LDS ranks — NO global atomics ----------
__global__ void __launch_bounds__(256) scatter_kernel(
    const int*   __restrict__ r_idx,
    const int*   __restrict__ h_idx,
    const int*   __restrict__ t_idx,
    const float* __restrict__ labels,
    const int*   __restrict__ blockoff,  // [NHBLK][512]
    int4*        __restrict__ quad)      // [BATCH] (h, t, b, label_bits)
{
    __shared__ int lcnt[512];
    const int tid = threadIdx.x;
    lcnt[tid] = 0; lcnt[tid + 256] = 0;
    __syncthreads();
    const int i    = blockIdx.x * 256 + tid;
    const int r    = r_idx[i];
    const int rank = atomicAdd(&lcnt[r], 1);            // LDS atomic (in-CU)
    const int pos  = blockoff[blockIdx.x * 512 + r] + rank;
    quad[pos] = make_int4(h_idx[i], t_idx[i], i, __float_as_int(labels[i]));
}

// ---------- K4: main — one block per chunk of 8; R streamed in 4-row groups ----------
__global__ void __launch_bounds__(256) rescal_main_kernel(
    const int4*  __restrict__ chunk_info,
    const int4*  __restrict__ quad,
    const float* __restrict__ ent_w,
    const float* __restrict__ rel_w,
    float*       __restrict__ scores_out,   // d_out + 1
    float4*      __restrict__ chunk_out)    // [MAXCHUNKS] (errS, htS, cnt*r2, 0)
{
    // bijective XCD swizzle: consecutive cids (same relation) share an XCD L2
    const int bid = blockIdx.x;
    const int xcd = bid & 7;
    const int j   = bid >> 3;
    const int q   = MAXCHUNKS / 8;
    const int r_  = MAXCHUNKS % 8;
    const int cid = (xcd < r_ ? xcd * (q + 1) : r_ * (q + 1) + (xcd - r_) * q) + j;

    const int4 ci    = chunk_info[cid];
    const int  rel   = ci.x;
    const int  start = ci.y;
    const int  e_cnt = ci.z;
    if (e_cnt == 0) return;                  // padded slot

    const int tid = threadIdx.x;
    const int w   = tid >> 6;
    const int l   = tid & 63;
    const int hi  = l >> 5;
    const int c4  = l & 31;
    const int rbase = 32 * w + 16 * hi;

    __shared__ float t_lds[CHUNK][DIM];
    __shared__ float h_lds[CHUNK][DIM];
    __shared__ float red[4][CHUNK];
    __shared__ float ht_red[CHUNK];
    __shared__ float d2s[CHUNK];
    __shared__ float r2_red[4];

    // ---- stage t, h (32 threads per element, 1 float4 each) ----
    const int eg   = tid >> 5;
    const int col4 = tid & 31;
    float4 tv4 = make_float4(0.f, 0.f, 0.f, 0.f);
    float4 hv4 = tv4;
    if (eg < e_cnt) {
        const int4 qd = quad[start + eg];
        hv4 = *(const float4*)(ent_w + (size_t)qd.x * DIM + col4 * 4);
        tv4 = *(const float4*)(ent_w + (size_t)qd.y * DIM + col4 * 4);
    }
    *(float4*)&t_lds[eg][col4 * 4] = tv4;
    *(float4*)&h_lds[eg][col4 * 4] = hv4;

    float htp = dot4(tv4, tv4) + dot4(hv4, hv4);
    #pragma unroll
    for (int off = 16; off >= 1; off >>= 1) htp += __shfl_xor(htp, off);
    if ((tid & 31) == 0) ht_red[eg] = htp;
    __syncthreads();

    // ---- t fragments to registers (b128, conflict-free) ----
    float4 t4[CHUNK];
    #pragma unroll
    for (int e = 0; e < CHUNK; ++e)
        t4[e] = *(const float4*)&t_lds[e][c4 * 4];

    // ---- stream R in 4-row groups (only 16 R-regs live) ----
    const float4* Rb = (const float4*)(rel_w + (size_t)rel * (DIM * DIM)
                                             + (size_t)rbase * DIM) + c4;
    float acc[CHUNK];
    #pragma unroll
    for (int e = 0; e < CHUNK; ++e) acc[e] = 0.f;
    float r2 = 0.f;

    #pragma unroll 1
    for (int pg = 0; pg < 4; ++pg) {
        const float4 r0 = Rb[(4 * pg + 0) * (DIM / 4)];
        const float4 r1 = Rb[(4 * pg + 1) * (DIM / 4)];
        const float4 rq = Rb[(4 * pg + 2) * (DIM / 4)];
        const float4 r3 = Rb[(4 * pg + 3) * (DIM / 4)];
        r2 += dot4(r0, r0) + dot4(r1, r1) + dot4(rq, rq) + dot4(r3, r3);
        #pragma unroll
        for (int e = 0; e < CHUNK; ++e) {
            const float4 h4 = *(const float4*)&h_lds[e][rbase + 4 * pg];
            acc[e] += h4.x * dot4(r0, t4[e]) + h4.y * dot4(r1, t4[e])
                    + h4.z * dot4(rq, t4[e]) + h4.w * dot4(r3, t4[e]);
        }
    }

    // ---- reductions (slot-invariant trees -> scores bit-stable) ----
    #pragma unroll
    for (int off = 32; off >= 1; off >>= 1) r2 += __shfl_xor(r2, off);
    if (l == 0) r2_red[w] = r2;

    #pragma unroll
    for (int e = 0; e < CHUNK; ++e) {
        float v = acc[e];
        #pragma unroll
        for (int off = 32; off >= 1; off >>= 1) v += __shfl_xor(v, off);
        if (l == 0) red[w][e] = v;
    }
    __syncthreads();

    if (tid < e_cnt) {
        const float s  = red[0][tid] + red[1][tid] + red[2][tid] + red[3][tid];
        const int4 qd  = quad[start + tid];          // L1-hot reread
        scores_out[qd.z] = s;
        const float d  = s - __int_as_float(qd.w);
        d2s[tid] = d * d;
    }
    __syncthreads();

    if (tid == 0) {
        float err = 0.f, ht = 0.f;
        for (int e = 0; e < e_cnt; ++e) { err += d2s[e]; ht += ht_red[e]; }
        const float r2t = r2_red[0] + r2_red[1] + r2_red[2] + r2_red[3];
        chunk_out[cid] = make_float4(err, ht, (float)e_cnt * r2t, 0.f);
    }
}

// ---------- K5: final — fixed-order reduction over chunk_out -> loss ----------
__global__ void __launch_bounds__(256) final_kernel(
    const float4* __restrict__ chunk_out,
    const int*    __restrict__ n_chunks,
    float*        __restrict__ loss_out)
{
    const int tid = threadIdx.x;
    const int total = n_chunks[0];
    float err = 0.f, ht = 0.f, r2 = 0.f;
    for (int i = tid; i < total; i += 256) {
        const float4 c = chunk_out[i];
        err += c.x; ht += c.y; r2 += c.z;
    }
    __shared__ float re[4], rh[4], rr2[4];
    #pragma unroll
    for (int off = 32; off >= 1; off >>= 1) {
        err += __shfl_down(err, off);
        ht  += __shfl_down(ht, off);
        r2  += __shfl_down(r2, off);
    }
    if ((tid & 63) == 0) { const int v = tid >> 6; re[v] = err; rh[v] = ht; rr2[v] = r2; }
    __syncthreads();
    if (tid == 0) {
        err = re[0] + re[1] + re[2] + re[3];
        ht  = rh[0] + rh[1] + rh[2] + rh[3];
        r2  = rr2[0] + rr2[1] + rr2[2] + rr2[3];
        const float mse   = err / (float)BATCH;
        const float norms = (ht / ((float)BATCH * DIM)
                           + r2 / ((float)BATCH * (float)(DIM * DIM))) / 3.0f;
        loss_out[0] = mse + ALPHA * norms;
    }
}

extern "C" void kernel_launch(void* const* d_in, const int* in_sizes, int n_in,
                              void* d_out, int out_size, void* d_ws, size_t ws_size,
                              hipStream_t stream) {
    const int*   h_idx  = (const int*)d_in[0];
    const int*   r_idx  = (const int*)d_in[1];
    const int*   t_idx  = (const int*)d_in[2];
    const float* labels = (const float*)d_in[3];
    const float* ent_w  = (const float*)d_in[4];
    const float* rel_w  = (const float*)d_in[5];

    float* out = (float*)d_out;   // [0]=loss, [1..BATCH]=scores

    // workspace layout (~600 KB)
    char* ws = (char*)d_ws;
    int4*   quad       = (int4*)ws;             ws += BATCH * sizeof(int4);          // 256K
    int*    partial_h  = (int*)ws;              ws += NHBLK * 512 * sizeof(int);     // 128K
    int*    blockoff   = (int*)ws;              ws += NHBLK * 512 * sizeof(int);     // 128K
    int4*   chunk_info = (int4*)ws;             ws += MAXCHUNKS * sizeof(int4);      // ~40K
    float4* chunk_out  = (float4*)ws;           ws += MAXCHUNKS * sizeof(float4);    // ~40K
    int*    n_chunks   = (int*)ws;

    parthist_kernel<<<NHBLK, 256, 0, stream>>>(r_idx, partial_h);
    scan_kernel<<<1, 512, 0, stream>>>(partial_h, blockoff, chunk_info, n_chunks);
    scatter_kernel<<<NHBLK, 256, 0, stream>>>(r_idx, h_idx, t_idx, labels,
                                              blockoff, quad);
    rescal_main_kernel<<<MAXCHUNKS, 256, 0, stream>>>(
        chunk_info, quad, ent_w, rel_w, out + 1, chunk_out);
    final_kernel<<<1, 256, 0, stream>>>(chunk_out, n_chunks, out);
}

// Round 9
// 46.758 us; speedup vs baseline: 1.6198x; 1.0742x over previous
//
#include <hip/hip_runtime.h>

#define DIM       128
#define BATCH     16384
#define RELN      500
#define ALPHA     0.001f
#define CHUNK     8
#define MAXCHUNKS (BATCH / CHUNK + RELN)   // 2548 upper bound on total chunks
#define PBLK      32                       // prep blocks (512 threads each)

__device__ __forceinline__ float dot4(float4 a, float4 b) {
    return a.x * b.x + a.y * b.y + a.z * b.z + a.w * b.w;
}

// ---------- K1: fused prep — hist + scan + scatter + chunk_info, LDS only ----------
// 32 blocks x 512 threads. Each block histograms ALL of r_idx (order-invariant)
// and its prefix region, scans in LDS, and scatters its own 512 elements with
// LDS-atomic ranks. Block 0 builds chunk_info. No global atomics, no serial
// latency chains, no intermediate global arrays.
__global__ void __launch_bounds__(512) prep_kernel(
    const int*   __restrict__ r_idx,
    const int*   __restrict__ h_idx,
    const int*   __restrict__ t_idx,
    const float* __restrict__ labels,
    int4*        __restrict__ quad,        // [BATCH] (h, t, b, label_bits)
    int4*        __restrict__ chunk_info)  // [MAXCHUNKS] (rel, start, e_cnt, 0)
{
    __shared__ int cntAll[512];
    __shared__ int cntPre[512];
    __shared__ int sc[512];
    __shared__ int exclA[512];
    const int tid     = threadIdx.x;
    const int bid     = blockIdx.x;
    const int myStart = bid * 512;

    cntAll[tid] = 0;
    cntPre[tid] = 0;
    __syncthreads();

    // full + prefix histograms (LDS atomics; counts are order-invariant)
    #pragma unroll 4
    for (int k = 0; k < BATCH / 512; ++k) {
        const int i = tid + k * 512;           // coalesced
        const int r = r_idx[i];
        atomicAdd(&cntAll[r], 1);
        if (i < myStart) atomicAdd(&cntPre[r], 1);
    }
    __syncthreads();

    // inclusive scan of cntAll -> excl
    sc[tid] = cntAll[tid];
    __syncthreads();
    for (int d = 1; d < 512; d <<= 1) {
        const int x = (tid >= d) ? sc[tid - d] : 0;
        __syncthreads();
        sc[tid] += x;
        __syncthreads();
    }
    exclA[tid] = sc[tid] - cntAll[tid];
    __syncthreads();

    // scatter own element: pos = excl[r] + (#prior with r) + rank
    {
        const int i = myStart + tid;
        const int r = r_idx[i];
        const int pos = exclA[r] + atomicAdd(&cntPre[r], 1);
        quad[pos] = make_int4(h_idx[i], t_idx[i], i, __float_as_int(labels[i]));
    }

    // block 0: chunk list (+ zero tail). Uniform branch; internal barriers OK.
    if (bid == 0) {
        const int cnt = cntAll[tid];
        const int nc  = (tid < RELN) ? (cnt + CHUNK - 1) / CHUNK : 0;
        __syncthreads();
        sc[tid] = nc;
        __syncthreads();
        for (int d = 1; d < 512; d <<= 1) {
            const int x = (tid >= d) ? sc[tid - d] : 0;
            __syncthreads();
            sc[tid] += x;
            __syncthreads();
        }
        const int cbase = sc[tid] - nc;
        const int total = sc[511];
        for (int i = 0; i < nc; ++i)
            chunk_info[cbase + i] = make_int4(
                tid, exclA[tid] + i * CHUNK, min(CHUNK, cnt - i * CHUNK), 0);
        for (int p = total + tid; p < MAXCHUNKS; p += 512)
            chunk_info[p] = make_int4(0, 0, 0, 0);
    }
}

// ---------- K2: main — one block per chunk of 8; R streamed in 4-row groups ----------
__global__ void __launch_bounds__(256) rescal_main_kernel(
    const int4*  __restrict__ chunk_info,
    const int4*  __restrict__ quad,
    const float* __restrict__ ent_w,
    const float* __restrict__ rel_w,
    float*       __restrict__ scores_out,   // d_out + 1
    float4*      __restrict__ chunk_out)    // [MAXCHUNKS] (errS, htS, cnt*r2, 0)
{
    // bijective XCD swizzle: consecutive cids (same relation) share an XCD L2
    const int bid = blockIdx.x;
    const int xcd = bid & 7;
    const int j   = bid >> 3;
    const int q   = MAXCHUNKS / 8;
    const int r_  = MAXCHUNKS % 8;
    const int cid = (xcd < r_ ? xcd * (q + 1) : r_ * (q + 1) + (xcd - r_) * q) + j;

    const int tid = threadIdx.x;

    const int4 ci    = chunk_info[cid];
    const int  rel   = ci.x;
    const int  start = ci.y;
    const int  e_cnt = ci.z;
    if (e_cnt == 0) {                        // padded slot: zero for final's pass
        if (tid == 0) chunk_out[cid] = make_float4(0.f, 0.f, 0.f, 0.f);
        return;
    }

    const int w   = tid >> 6;
    const int l   = tid & 63;
    const int hi  = l >> 5;
    const int c4  = l & 31;
    const int rbase = 32 * w + 16 * hi;

    __shared__ float t_lds[CHUNK][DIM];
    __shared__ float h_lds[CHUNK][DIM];
    __shared__ float red[4][CHUNK];
    __shared__ float ht_red[CHUNK];
    __shared__ float d2s[CHUNK];
    __shared__ float r2_red[4];

    // ---- stage t, h (32 threads per element, 1 float4 each) ----
    const int eg   = tid >> 5;
    const int col4 = tid & 31;
    float4 tv4 = make_float4(0.f, 0.f, 0.f, 0.f);
    float4 hv4 = tv4;
    if (eg < e_cnt) {
        const int4 qd = quad[start + eg];
        hv4 = *(const float4*)(ent_w + (size_t)qd.x * DIM + col4 * 4);
        tv4 = *(const float4*)(ent_w + (size_t)qd.y * DIM + col4 * 4);
    }
    *(float4*)&t_lds[eg][col4 * 4] = tv4;
    *(float4*)&h_lds[eg][col4 * 4] = hv4;

    float htp = dot4(tv4, tv4) + dot4(hv4, hv4);
    #pragma unroll
    for (int off = 16; off >= 1; off >>= 1) htp += __shfl_xor(htp, off);
    if ((tid & 31) == 0) ht_red[eg] = htp;
    __syncthreads();

    // ---- t fragments to registers (b128, conflict-free) ----
    float4 t4[CHUNK];
    #pragma unroll
    for (int e = 0; e < CHUNK; ++e)
        t4[e] = *(const float4*)&t_lds[e][c4 * 4];

    // ---- stream R in 4-row groups (only 16 R-regs live) ----
    const float4* Rb = (const float4*)(rel_w + (size_t)rel * (DIM * DIM)
                                             + (size_t)rbase * DIM) + c4;
    float acc[CHUNK];
    #pragma unroll
    for (int e = 0; e < CHUNK; ++e) acc[e] = 0.f;
    float r2 = 0.f;

    #pragma unroll 1
    for (int pg = 0; pg < 4; ++pg) {
        const float4 r0 = Rb[(4 * pg + 0) * (DIM / 4)];
        const float4 r1 = Rb[(4 * pg + 1) * (DIM / 4)];
        const float4 rq = Rb[(4 * pg + 2) * (DIM / 4)];
        const float4 r3 = Rb[(4 * pg + 3) * (DIM / 4)];
        r2 += dot4(r0, r0) + dot4(r1, r1) + dot4(rq, rq) + dot4(r3, r3);
        #pragma unroll
        for (int e = 0; e < CHUNK; ++e) {
            const float4 h4 = *(const float4*)&h_lds[e][rbase + 4 * pg];
            acc[e] += h4.x * dot4(r0, t4[e]) + h4.y * dot4(r1, t4[e])
                    + h4.z * dot4(rq, t4[e]) + h4.w * dot4(r3, t4[e]);
        }
    }

    // ---- reductions (slot-invariant trees -> scores bit-stable) ----
    #pragma unroll
    for (int off = 32; off >= 1; off >>= 1) r2 += __shfl_xor(r2, off);
    if (l == 0) r2_red[w] = r2;

    #pragma unroll
    for (int e = 0; e < CHUNK; ++e) {
        float v = acc[e];
        #pragma unroll
        for (int off = 32; off >= 1; off >>= 1) v += __shfl_xor(v, off);
        if (l == 0) red[w][e] = v;
    }
    __syncthreads();

    if (tid < e_cnt) {
        const float s  = red[0][tid] + red[1][tid] + red[2][tid] + red[3][tid];
        const int4 qd  = quad[start + tid];          // L1-hot reread
        scores_out[qd.z] = s;
        const float d  = s - __int_as_float(qd.w);
        d2s[tid] = d * d;
    }
    __syncthreads();

    if (tid == 0) {
        float err = 0.f, ht = 0.f;
        for (int e = 0; e < e_cnt; ++e) { err += d2s[e]; ht += ht_red[e]; }
        const float r2t = r2_red[0] + r2_red[1] + r2_red[2] + r2_red[3];
        chunk_out[cid] = make_float4(err, ht, (float)e_cnt * r2t, 0.f);
    }
}

// ---------- K3: final — fixed-order reduction over full chunk_out -> loss ----------
__global__ void __launch_bounds__(256) final_kernel(
    const float4* __restrict__ chunk_out,
    float*        __restrict__ loss_out)
{
    const int tid = threadIdx.x;
    float err = 0.f, ht = 0.f, r2 = 0.f;
    for (int i = tid; i < MAXCHUNKS; i += 256) {
        const float4 c = chunk_out[i];
        err += c.x; ht += c.y; r2 += c.z;
    }
    __shared__ float re[4], rh[4], rr2[4];
    #pragma unroll
    for (int off = 32; off >= 1; off >>= 1) {
        err += __shfl_down(err, off);
        ht  += __shfl_down(ht, off);
        r2  += __shfl_down(r2, off);
    }
    if ((tid & 63) == 0) { const int v = tid >> 6; re[v] = err; rh[v] = ht; rr2[v] = r2; }
    __syncthreads();
    if (tid == 0) {
        err = re[0] + re[1] + re[2] + re[3];
        ht  = rh[0] + rh[1] + rh[2] + rh[3];
        r2  = rr2[0] + rr2[1] + rr2[2] + rr2[3];
        const float mse   = err / (float)BATCH;
        const float norms = (ht / ((float)BATCH * DIM)
                           + r2 / ((float)BATCH * (float)(DIM * DIM))) / 3.0f;
        loss_out[0] = mse + ALPHA * norms;
    }
}

extern "C" void kernel_launch(void* const* d_in, const int* in_sizes, int n_in,
                              void* d_out, int out_size, void* d_ws, size_t ws_size,
                              hipStream_t stream) {
    const int*   h_idx  = (const int*)d_in[0];
    const int*   r_idx  = (const int*)d_in[1];
    const int*   t_idx  = (const int*)d_in[2];
    const float* labels = (const float*)d_in[3];
    const float* ent_w  = (const float*)d_in[4];
    const float* rel_w  = (const float*)d_in[5];

    float* out = (float*)d_out;   // [0]=loss, [1..BATCH]=scores

    // workspace layout (~340 KB)
    char* ws = (char*)d_ws;
    int4*   quad       = (int4*)ws;             ws += BATCH * sizeof(int4);        // 256K
    int4*   chunk_info = (int4*)ws;             ws += MAXCHUNKS * sizeof(int4);    // ~40K
    float4* chunk_out  = (float4*)ws;           // ~40K

    prep_kernel<<<PBLK, 512, 0, stream>>>(r_idx, h_idx, t_idx, labels,
                                          quad, chunk_info);
    rescal_main_kernel<<<MAXCHUNKS, 256, 0, stream>>>(
        chunk_info, quad, ent_w, rel_w, out + 1, chunk_out);
    final_kernel<<<1, 256, 0, stream>>>(chunk_out, out);
}